// Round 9
// baseline (445.925 us; speedup 1.0000x reference)
//
#include <hip/hip_runtime.h>
#include <hip/hip_bf16.h>
#include <cstdint>

#define NND 100000
#define NED 1600000
#define FIN 128
#define FOUT 64

// bucket-sort CSR parameters
#define NBLK 256              // histogram/scatter blocks
#define EPB (NED / NBLK)      // 6250 edges per block (exact)
#define NBUCK 256             // coarse buckets
#define BSH 9                 // bucket = dst >> 9
#define BNODES 512            // nodes per bucket
#define HTN (NBUCK * NBLK)    // histT length = 65536

typedef __bf16 bf16x8 __attribute__((ext_vector_type(8)));
typedef float f32x4 __attribute__((ext_vector_type(4)));

static __device__ inline unsigned short f2bf(float f) {
    unsigned int u = __builtin_bit_cast(unsigned int, f);
    unsigned int r = (u + 0x7fffu + ((u >> 16) & 1u)) >> 16;  // RNE
    return (unsigned short)r;
}
static __device__ inline float bflo(unsigned int v) {
    return __builtin_bit_cast(float, v << 16);
}
static __device__ inline float bfhi(unsigned int v) {
    return __builtin_bit_cast(float, v & 0xffff0000u);
}
static __device__ inline float bf1(unsigned short u) {
    return __builtin_bit_cast(float, (unsigned int)u << 16);
}

// ---------------- weight pack into MFMA B-fragment order ----------------
static __device__ inline void pack_one(const float* __restrict__ W,
                                       unsigned short* __restrict__ out,
                                       int NTtot, int c_local, int nt,
                                       int chunkOff, int ncols, int lane) {
    int k = c_local * 32 + (lane >> 4) * 8;
    int n = nt * 16 + (lane & 15);
    unsigned short t[8];
#pragma unroll
    for (int j = 0; j < 8; j++) t[j] = f2bf(W[(size_t)(k + j) * ncols + n]);
    uint4 u;
    u.x = t[0] | ((unsigned)t[1] << 16);
    u.y = t[2] | ((unsigned)t[3] << 16);
    u.z = t[4] | ((unsigned)t[5] << 16);
    u.w = t[6] | ((unsigned)t[7] << 16);
    *(uint4*)&out[((size_t)((c_local + chunkOff) * NTtot + nt) * 64 + lane) * 8] = u;
}

// ---------------- K1: per-block bucket histogram + x cast + weight pack ----
__global__ __launch_bounds__(256) void k_hist_cast(
        const int* __restrict__ dst, int* __restrict__ histT,
        const float* __restrict__ x, unsigned int* __restrict__ xb,
        const float* W1l, const float* W1r, const float* W2l,
        const float* W2r, const float* Wlin,
        unsigned short* p1, unsigned short* p2, unsigned short* ph) {
    __shared__ int hist[NBUCK];
    const int tid = threadIdx.x, blk = blockIdx.x;
    hist[tid] = 0;  // 256 threads == NBUCK
    __syncthreads();
    const int e0 = blk * EPB, e1 = e0 + EPB;
    for (int i = e0 + tid; i < e1; i += 256)
        atomicAdd(&hist[dst[i] >> BSH], 1);   // LDS atomic
    __syncthreads();
    histT[tid * NBLK + blk] = hist[tid];
    // fused weight pack (blocks 0..143, first wave)
    if (blk < 144 && tid < 64) {
        int b = blk, lane = tid;
        if (b < 32)       pack_one(W1l, p1, 8, b >> 3, b & 7, 0, 128, lane);
        else if (b < 64)  { b -= 32; pack_one(W1r, p1, 8, b >> 3, b & 7, 4, 128, lane); }
        else if (b < 96)  { b -= 64; pack_one(W2l, p2, 8, b >> 3, b & 7, 0, 128, lane); }
        else if (b < 128) { b -= 96; pack_one(W2r, p2, 8, b >> 3, b & 7, 4, 128, lane); }
        else              { b -= 128; pack_one(Wlin, ph, 4, b >> 2, b & 3, 0, 64, lane); }
    }
    // fused cast: grid-stride over N*64 float2
    const int total2 = NND * 64;
    for (int i = blk * 256 + tid; i < total2; i += NBLK * 256) {
        float2 v = ((const float2*)x)[i];
        xb[i] = (unsigned int)f2bf(v.x) | ((unsigned int)f2bf(v.y) << 16);
    }
}

// ---------------- generic hierarchical exclusive scan ----------------
__global__ __launch_bounds__(1024) void g_scan1(const int* __restrict__ in,
                                                int* __restrict__ psum, int n) {
    __shared__ int red[1024];
    int tid = threadIdx.x;
    int i = blockIdx.x * 1024 + tid;
    red[tid] = (i < n) ? in[i] : 0;
    __syncthreads();
#pragma unroll
    for (int off = 512; off > 0; off >>= 1) {
        if (tid < off) red[tid] += red[tid + off];
        __syncthreads();
    }
    if (tid == 0) psum[blockIdx.x] = red[0];
}

__global__ __launch_bounds__(128) void g_scan2(int* __restrict__ psum, int nb) {
    int tid = threadIdx.x;
    int d = (tid < nb) ? psum[tid] : 0;
    int v = d;
#pragma unroll
    for (int off = 1; off < 64; off <<= 1) {
        int u = __shfl_up(v, off, 64);
        if ((tid & 63) >= off) v += u;
    }
    __shared__ int ws[2];
    if ((tid & 63) == 63) ws[tid >> 6] = v;
    __syncthreads();
    int base = (tid >= 64) ? ws[0] : 0;
    if (tid < nb) psum[tid] = base + v - d;
}

__global__ __launch_bounds__(1024) void g_scan3(const int* __restrict__ in,
                                                const int* __restrict__ psum,
                                                int* __restrict__ out, int n) {
    int tid = threadIdx.x;
    int i = blockIdx.x * 1024 + tid;
    int d = (i < n) ? in[i] : 0;
    int v = d;
#pragma unroll
    for (int off = 1; off < 64; off <<= 1) {
        int u = __shfl_up(v, off, 64);
        if ((tid & 63) >= off) v += u;
    }
    __shared__ int wsum[16];
    int wid = tid >> 6;
    if ((tid & 63) == 63) wsum[wid] = v;
    __syncthreads();
    if (tid < 16) {
        int w = wsum[tid];
#pragma unroll
        for (int off = 1; off < 16; off <<= 1) {
            int u = __shfl_up(w, off, 64);
            if (tid >= off) w += u;
        }
        wsum[tid] = w;
    }
    __syncthreads();
    int base = psum[blockIdx.x] + (wid ? wsum[wid - 1] : 0);
    if (i < n) out[i] = base + v - d;
}

// ---------------- K3: coarse scatter into bucket-grouped packed pairs ------
// packed edge = (localdst << 20) | src   (src < 2^17, localdst < 512)
__global__ __launch_bounds__(256) void k_scatter(const int* __restrict__ src,
                                                 const int* __restrict__ dst,
                                                 const int* __restrict__ sh,
                                                 unsigned int* __restrict__ eS) {
    __shared__ int cur[NBUCK];
    const int tid = threadIdx.x, blk = blockIdx.x;
    cur[tid] = sh[tid * NBLK + blk];
    __syncthreads();
    const int e0 = blk * EPB, e1 = e0 + EPB;
    for (int i = e0 + tid; i < e1; i += 256) {
        int d = dst[i];
        int pos = atomicAdd(&cur[d >> BSH], 1);   // LDS atomic
        eS[pos] = ((unsigned)(d & (BNODES - 1)) << 20) | (unsigned)src[i];
    }
}

// ---------------- K4: per-bucket counting sort -> csr, offs, dinv ----------
__global__ __launch_bounds__(1024) void k_bucket(const unsigned int* __restrict__ eS,
                                                 const int* __restrict__ sh,
                                                 int* __restrict__ csr,
                                                 int* __restrict__ offs,
                                                 float* __restrict__ dinv, int n) {
    __shared__ int cnt[BNODES];
    __shared__ int loc[BNODES];
    const int b = blockIdx.x, tid = threadIdx.x;
    const int base = sh[b * NBLK];
    const int end = (b == NBUCK - 1) ? NED : sh[(b + 1) * NBLK];
    if (tid < BNODES) cnt[tid] = 0;
    __syncthreads();
    for (int i = base + tid; i < end; i += 1024)
        atomicAdd(&cnt[eS[i] >> 20], 1);          // LDS atomic
    __syncthreads();
    if (tid < BNODES) loc[tid] = cnt[tid];
    __syncthreads();
#pragma unroll
    for (int off = 1; off < BNODES; off <<= 1) {
        int v = 0;
        if (tid < BNODES && tid >= off) v = loc[tid - off];
        __syncthreads();
        if (tid < BNODES) loc[tid] += v;
        __syncthreads();
    }
    int node = b * BNODES + tid;
    int myExcl = 0;
    if (tid < BNODES) {
        myExcl = loc[tid] - cnt[tid];  // exclusive
        if (node < n) {
            offs[node] = base + myExcl;
            dinv[node] = 1.0f / fmaxf((float)cnt[tid], 1.0f);
        }
    }
    __syncthreads();
    if (tid < BNODES) cnt[tid] = base + myExcl;  // running cursor
    __syncthreads();
    for (int i = base + tid; i < end; i += 1024) {
        unsigned int e = eS[i];
        int slot = atomicAdd(&cnt[e >> 20], 1);   // LDS atomic
        csr[slot] = (int)(e & 0xFFFFFu);
    }
    if (b == 0 && tid == 0) offs[n] = NED;
}

// ---------------- fused aggregate + MFMA GEMM (+optional head) -------------
// Block = 64 rows, 4 waves. Each wave aggregates its own 16 nodes into a
// wave-private LDS region (row stride 136 halves -> only free 2-way bank
// aliasing), then feeds MFMA A-fragments for chunks 0..3 from LDS and
// chunks 4..7 (the lin_r operand) from global Q. No __syncthreads needed.
#define ACC8(v) do { \
    acc[0].x += bflo((v).x); acc[0].y += bfhi((v).x); \
    acc[1].x += bflo((v).y); acc[1].y += bfhi((v).y); \
    acc[2].x += bflo((v).z); acc[2].y += bfhi((v).z); \
    acc[3].x += bflo((v).w); acc[3].y += bfhi((v).w); } while (0)

template <bool RESID, bool HEAD, bool OUTBF>
__global__ __launch_bounds__(256) void k_agg_mfma(
        const uint4* __restrict__ feat4,       // gather source (bf16 rows)
        const unsigned short* __restrict__ Q,  // dense operand / resid
        const int* __restrict__ offs, const int* __restrict__ csr,
        const float* __restrict__ dinv,
        const unsigned short* __restrict__ Wp, const float* __restrict__ bias,
        const unsigned short* __restrict__ Wp2, const float* __restrict__ bias2,
        void* __restrict__ outv, int n) {
    const int tid = threadIdx.x;
    const int lane = tid & 63, wave = tid >> 6;
    const int grp = lane >> 4, ch = lane & 15;
    const int row0 = blockIdx.x * 64;

    __shared__ __align__(16) unsigned short sAgg[64 * 136];

    // ---- phase 1: aggregate wave's 16 nodes ----
    for (int nn = 0; nn < 16; nn++) {
        int node = row0 + wave * 16 + nn;
        int nd = node < n ? node : n - 1;  // pad rows: junk, masked at store
        int beg = offs[nd], end = offs[nd + 1];
        int deg = end - beg;
        float2 acc[4];
#pragma unroll
        for (int j = 0; j < 4; j++) acc[j] = make_float2(0.f, 0.f);
        int i = beg;
        int fullEnd = beg + (deg & ~15);
        for (; i < fullEnd; i += 16) {  // 4 gathers in flight, no masks
            int s0 = csr[i + grp];
            int s1 = csr[i + 4 + grp];
            int s2 = csr[i + 8 + grp];
            int s3 = csr[i + 12 + grp];
            uint4 v0 = feat4[(size_t)s0 * 16 + ch];
            uint4 v1 = feat4[(size_t)s1 * 16 + ch];
            uint4 v2 = feat4[(size_t)s2 * 16 + ch];
            uint4 v3 = feat4[(size_t)s3 * 16 + ch];
            ACC8(v0); ACC8(v1); ACC8(v2); ACC8(v3);
        }
        if (i < end) {  // tail <= 15 edges, predicated
#pragma unroll
            for (int g = 0; g < 4; g++) {
                int e = i + g * 4 + grp;
                bool p = e < end;
                int s = csr[p ? e : beg];
                uint4 v = feat4[(size_t)s * 16 + ch];
                if (p) { ACC8(v); }
            }
        }
#pragma unroll
        for (int j = 0; j < 4; j++) {
            acc[j].x += __shfl_xor(acc[j].x, 16);
            acc[j].y += __shfl_xor(acc[j].y, 16);
            acc[j].x += __shfl_xor(acc[j].x, 32);
            acc[j].y += __shfl_xor(acc[j].y, 32);
        }
        if (grp == 0) {
            float di = dinv[nd];
            uint4 o;
            o.x = (unsigned)f2bf(acc[0].x * di) | ((unsigned)f2bf(acc[0].y * di) << 16);
            o.y = (unsigned)f2bf(acc[1].x * di) | ((unsigned)f2bf(acc[1].y * di) << 16);
            o.z = (unsigned)f2bf(acc[2].x * di) | ((unsigned)f2bf(acc[2].y * di) << 16);
            o.w = (unsigned)f2bf(acc[3].x * di) | ((unsigned)f2bf(acc[3].y * di) << 16);
            *(uint4*)&sAgg[(wave * 16 + nn) * 136 + ch * 8] = o;
        }
    }
    // wave-private: each wave reads only rows it wrote -> no barrier

    // ---- phase 2: MFMA ----
    const int quad = lane >> 4;
    const int m = lane & 15;
    int rowA = row0 + wave * 16 + m;
    int rowAc = rowA < n ? rowA : n - 1;

    f32x4 macc[8];
#pragma unroll
    for (int t = 0; t < 8; t++) macc[t] = (f32x4){0.f, 0.f, 0.f, 0.f};

#pragma unroll
    for (int c = 0; c < 8; c++) {
        bf16x8 a;
        if (c < 4)
            a = *(const bf16x8*)&sAgg[(wave * 16 + m) * 136 + c * 32 + quad * 8];
        else
            a = *(const bf16x8*)&Q[(size_t)rowAc * 128 + (c - 4) * 32 + quad * 8];
#pragma unroll
        for (int t = 0; t < 8; t++) {
            bf16x8 b = *(const bf16x8*)&Wp[(size_t)((c * 8 + t) * 64 + lane) * 8];
            macc[t] = __builtin_amdgcn_mfma_f32_16x16x32_bf16(a, b, macc[t], 0, 0, 0);
        }
    }

    const int col = lane & 15;
    if (!HEAD) {
#pragma unroll
        for (int t = 0; t < 8; t++) {
            float bv = bias[t * 16 + col];
#pragma unroll
            for (int r = 0; r < 4; r++) {
                int row = row0 + wave * 16 + quad * 4 + r;
                if (row < n) {
                    float v = macc[t][r] + bv;
                    if (RESID) v += bf1(Q[(size_t)row * 128 + t * 16 + col]);
                    v = fmaxf(v, 0.f);  // both layer kernels relu
                    if (OUTBF)
                        ((unsigned short*)outv)[(size_t)row * 128 + t * 16 + col] = f2bf(v);
                    else
                        ((float*)outv)[(size_t)row * 128 + t * 16 + col] = v;
                }
            }
        }
    } else {
        __shared__ __align__(16) unsigned short sT[4][16 * 136];
#pragma unroll
        for (int t = 0; t < 8; t++) {
            float bv = bias[t * 16 + col];
#pragma unroll
            for (int r = 0; r < 4; r++) {
                int row = row0 + wave * 16 + quad * 4 + r;
                int rr = row < n ? row : n - 1;
                float v = macc[t][r] + bv;
                if (RESID) v += bf1(Q[(size_t)rr * 128 + t * 16 + col]);
                v = fmaxf(v, 0.f);
                sT[wave][(quad * 4 + r) * 136 + t * 16 + col] = f2bf(v);
            }
        }
        f32x4 hacc[4];
#pragma unroll
        for (int t = 0; t < 4; t++) hacc[t] = (f32x4){0.f, 0.f, 0.f, 0.f};
#pragma unroll
        for (int c = 0; c < 4; c++) {
            bf16x8 a = *(const bf16x8*)&sT[wave][m * 136 + c * 32 + quad * 8];
#pragma unroll
            for (int t = 0; t < 4; t++) {
                bf16x8 b = *(const bf16x8*)&Wp2[(size_t)((c * 4 + t) * 64 + lane) * 8];
                hacc[t] = __builtin_amdgcn_mfma_f32_16x16x32_bf16(a, b, hacc[t], 0, 0, 0);
            }
        }
#pragma unroll
        for (int t = 0; t < 4; t++) {
            float bv = bias2[t * 16 + col];
#pragma unroll
            for (int r = 0; r < 4; r++) {
                int row = row0 + wave * 16 + quad * 4 + r;
                if (row < n)
                    ((float*)outv)[(size_t)row * 64 + t * 16 + col] = hacc[t][r] + bv;
            }
        }
    }
}

extern "C" void kernel_launch(void* const* d_in, const int* in_sizes, int n_in,
                              void* d_out, int out_size, void* d_ws, size_t ws_size,
                              hipStream_t stream) {
    const float* x    = (const float*)d_in[0];
    const int*   ei   = (const int*)d_in[1];
    const float* W1l  = (const float*)d_in[2];
    const float* b1   = (const float*)d_in[3];
    const float* W1r  = (const float*)d_in[4];
    const float* W2l  = (const float*)d_in[5];
    const float* b2   = (const float*)d_in[6];
    const float* W2r  = (const float*)d_in[7];
    const float* Wlin = (const float*)d_in[8];
    const float* blin = (const float*)d_in[9];
    float* out = (float*)d_out;

    const int N = NND, E = NED;
    const int* src = ei;
    const int* dst = ei + E;
    const int NB2 = HTN / 1024;  // 64 scan blocks

    char* w = (char*)d_ws;
    int*   histT  = (int*)w;               w += (size_t)HTN * 4;
    int*   sh     = (int*)w;               w += (size_t)HTN * 4;
    int*   psum   = (int*)w;               w += (size_t)NB2 * 4;
    int*   offs   = (int*)w;               w += (size_t)(N + 4) * 4;
    float* dinv   = (float*)w;             w += (size_t)N * 4;
    unsigned int* eS = (unsigned int*)w;   w += (size_t)E * 4;
    int*   csr    = (int*)w;               w += (size_t)E * 4;
    unsigned short* p1  = (unsigned short*)w;  w += 256 * 128 * 2;
    unsigned short* p2  = (unsigned short*)w;  w += 256 * 128 * 2;
    unsigned short* ph  = (unsigned short*)w;  w += 128 * 64 * 2;
    unsigned short* xb  = (unsigned short*)w;  w += (size_t)N * 128 * 2;
    unsigned short* h1  = (unsigned short*)w;  w += (size_t)N * 128 * 2;

    // CSR build: zero global atomics
    k_hist_cast<<<NBLK, 256, 0, stream>>>(dst, histT, x, (unsigned int*)xb,
                                          W1l, W1r, W2l, W2r, Wlin, p1, p2, ph);
    g_scan1<<<NB2, 1024, 0, stream>>>(histT, psum, HTN);
    g_scan2<<<1, 128, 0, stream>>>(psum, NB2);
    g_scan3<<<NB2, 1024, 0, stream>>>(histT, psum, sh, HTN);
    k_scatter<<<NBLK, 256, 0, stream>>>(src, dst, sh, eS);
    k_bucket<<<NBUCK, 1024, 0, stream>>>(eS, sh, csr, offs, dinv, N);

    // layer 1 (fused agg+GEMM): h1 = relu([mean(xb[nb])|xb] @ [W1l;W1r] + b1)
    k_agg_mfma<false, false, true><<<(N + 63) / 64, 256, 0, stream>>>(
        (const uint4*)xb, xb, offs, csr, dinv, p1, b1, nullptr, nullptr, h1, N);

    // layer 2 + head (fused): out = relu(h1 + [mean(h1[nb])|h1]@[W2l;W2r]+b2) @ Wlin + blin
    k_agg_mfma<true, true, false><<<(N + 63) / 64, 256, 0, stream>>>(
        (const uint4*)h1, h1, offs, csr, dinv, p2, b2, ph, blin, out, N);
}